// Round 1
// baseline (150.171 us; speedup 1.0000x reference)
//
#include <hip/hip_runtime.h>
#include <math.h>

// CPNet registration: B=8 batches, pc1 (4 x 4096), pc2 (4 x 4096), fp32.
// Outputs: T (8,4,4)=128 | q (8,4)=32 | t (8,3)=24  -> 184 floats concat.
//
// R7: K1 kept VERBATIM (proven R3 two-pass packed softmax, 67us).
// K2+K3+K4 fused into ONE kernel (cpnet_finalize) via the deterministic
// last-block pattern: every block does K2's combine + dist partial
// (identical math), then threadfence + per-batch completion counter;
// the last-arriving block per batch computes the mean (same serial
// 16-term sum as before, bit-identical), the 23 moments over all 4096
// rows (double accumulators in registers -> block shuffle reduce), and
// the Jacobi/Horn solve inline on lane 0. Removes 2 kernel launches,
// the mpart HBM round-trip, and K4's serial 368-load accumulation.
// Atomics are used ONLY as a completion flag -- no numeric fan-in.
// Counter zero-init is folded into K1 block (0,0,0).

typedef float v2f __attribute__((ext_vector_type(2)));

constexpr int cB  = 8;
constexpr int cN1 = 4096;
constexpr int cN2 = 4096;
constexpr int cMC = 8;               // m-chunks
constexpr int cCHUNK = cN2 / cMC;    // 512
constexpr int cNB2 = cN1 / 256;      // 16 n-blocks for finalize
constexpr float cEPS  = 1e-5f;
constexpr float cKK   = 0.34657359027997264f;   // ln2/2 = 1/(FACT*log2(e))
constexpr float cEPSK = cEPS * cKK;             // scaled clamp
constexpr float cUNSC = -1.4426950408889634f;   // -1/ln2 (undo -ln2 packing)

// ---------------- workspace layout (bytes) ----------------
// partA : float4[cMC*cB*cN1] @ 0         (4 MiB; chunk 0 reused as near4)
// partM : float [cMC*cB*cN1] @ 0x400000  (1 MiB)
// dpart : double[cB*16]      @ 0x500000  (1 KiB)
// ctr   : int[cB]            @ 0x500400  (32 B, completion counters)
constexpr size_t OFF_PARTM = 0x400000;
constexpr size_t OFF_DPART = 0x500000;
constexpr size_t OFF_CTR   = 0x500400;

// ============ K1: R3's proven two-pass packed softmax partials =============
__global__ __launch_bounds__(256) void cpnet_partial(
    const float* __restrict__ pc1, const float* __restrict__ pc2,
    float4* __restrict__ partA, float* __restrict__ partM,
    int* __restrict__ ctr) {
  // fold completion-counter zeroing into K1 (runs before finalize in
  // stream order every iteration; covers poisoned-workspace semantics)
  if (blockIdx.x == 0 && blockIdx.y == 0 && blockIdx.z == 0 &&
      threadIdx.x < cB)
    ctr[threadIdx.x] = 0;

  __shared__ float xs[cCHUNK], ys[cCHUNK], zs[cCHUNK], ws[cCHUNK];
  const int tid = threadIdx.x;
  const int b = blockIdx.z, c = blockIdx.y;
  const int n = blockIdx.x * 256 + tid;

  // fused pack: (-ln2*x, -ln2*y, -ln2*z, (ln2/2)*|p|^2)
  const float* p2b = pc2 + (size_t)b * 4 * cN2 + c * cCHUNK;
  for (int i = tid; i < cCHUNK; i += 256) {
    float x = p2b[i], y = p2b[cN2 + i], z = p2b[2 * cN2 + i];
    xs[i] = -2.0f * cKK * x;
    ys[i] = -2.0f * cKK * y;
    zs[i] = -2.0f * cKK * z;
    ws[i] = cKK * (x * x + y * y + z * z);
  }
  __syncthreads();

  const float* p1b = pc1 + (size_t)b * 4 * cN1;
  const float x1 = p1b[n], y1 = p1b[cN1 + n], z1 = p1b[2 * cN1 + n];
  const float n1k = cKK * (x1 * x1 + y1 * y1 + z1 * z1);
  const v2f X1 = {x1, x1}, Y1 = {y1, y1}, Z1 = {z1, z1}, N1K = {n1k, n1k};

  const v2f* xs2 = (const v2f*)xs;
  const v2f* ys2 = (const v2f*)ys;
  const v2f* zs2 = (const v2f*)zs;
  const v2f* ws2 = (const v2f*)ws;

  // pass 1: min dk over chunk (dk = (ln2/2)*d; s2 = rcp(dk) monotone dec.)
  v2f dmin2 = {3.0e38f, 3.0e38f};
#pragma unroll 4
  for (int m = 0; m < cCHUNK / 2; ++m) {
    v2f dk = X1 * xs2[m] + (Y1 * ys2[m] + (Z1 * zs2[m] + (ws2[m] + N1K)));
    dmin2 = __builtin_elementwise_min(dmin2, dk);
  }
  const float dmin = fminf(dmin2.x, dmin2.y);
  const float M = __builtin_amdgcn_rcpf(fmaxf(dmin, cEPSK));
  const v2f M2 = {M, M};
  const v2f EPS2 = {cEPSK, cEPSK};

  // pass 2: exp-sum + weighted accumulators, e = exp2(s2 - M) <= 1
  v2f S2 = {0.f, 0.f}, Ax2 = {0.f, 0.f}, Ay2 = {0.f, 0.f}, Az2 = {0.f, 0.f};
#pragma unroll 4
  for (int m = 0; m < cCHUNK / 2; ++m) {
    v2f vx = xs2[m], vy = ys2[m], vz = zs2[m];
    v2f dk = X1 * vx + (Y1 * vy + (Z1 * vz + (ws2[m] + N1K)));
    dk = __builtin_elementwise_max(dk, EPS2);
    v2f s2v;
    s2v.x = __builtin_amdgcn_rcpf(dk.x);
    s2v.y = __builtin_amdgcn_rcpf(dk.y);
    v2f d2 = s2v - M2;
    v2f e;
    e.x = __builtin_amdgcn_exp2f(d2.x);
    e.y = __builtin_amdgcn_exp2f(d2.y);
    S2 += e;
    Ax2 += e * vx;
    Ay2 += e * vy;
    Az2 += e * vz;
  }

  const int idx = (c * cB + b) * cN1 + n;
  partA[idx] = make_float4(Ax2.x + Ax2.y, Ay2.x + Ay2.y, Az2.x + Az2.y,
                           S2.x + S2.y);
  partM[idx] = M;
}

// ---------------- batched block reduce (256 thr, 4 waves, doubles) ---------
__device__ __forceinline__ void reduce_multi(double* v, int nv, double* lds,
                                             int tid) {
  const int lane = tid & 63, w = tid >> 6;
  for (int i = 0; i < nv; ++i) {
    double x = v[i];
    for (int s = 32; s > 0; s >>= 1) x += __shfl_xor(x, s, 64);
    if (lane == 0) lds[i * 4 + w] = x;
  }
  __syncthreads();
  if (tid < nv)
    lds[tid * 4] = lds[tid * 4] + lds[tid * 4 + 1] + lds[tid * 4 + 2] +
                   lds[tid * 4 + 3];
  __syncthreads();
  for (int i = 0; i < nv; ++i) v[i] = lds[i * 4];
  __syncthreads();
}

// ============ K2': fused combine + moments + solve (last-block) ============
__global__ __launch_bounds__(256) void cpnet_finalize(
    const float* __restrict__ pc1, float4* partA,
    const float* __restrict__ partM, double* __restrict__ dpart,
    int* ctr, float* __restrict__ out) {
  __shared__ double lds[32 * 4];
  __shared__ float s_mean;
  __shared__ int s_last;
  const int tid = threadIdx.x;
  const int bx = blockIdx.x, b = blockIdx.y;
  const int n = bx * 256 + tid;

  // ---------- phase 1: K2's combine, verbatim ----------
  float Ms[cMC];
  float g = -3.0e38f;
#pragma unroll
  for (int c = 0; c < cMC; ++c) {
    Ms[c] = partM[(c * cB + b) * cN1 + n];
    g = fmaxf(g, Ms[c]);
  }
  float S = 0.f, nx = 0.f, ny = 0.f, nz = 0.f;
#pragma unroll
  for (int c = 0; c < cMC; ++c) {
    float w = exp2f(Ms[c] - g);
    float4 a4 = partA[(c * cB + b) * cN1 + n];
    S += a4.w * w; nx += a4.x * w; ny += a4.y * w; nz += a4.z * w;
  }
  float inv = cUNSC / S;         // undo -ln2 packing + softmax normalize
  nx *= inv; ny *= inv; nz *= inv;
  const float* p1b = pc1 + (size_t)b * 4 * cN1;
  float dx = p1b[n] - nx, dy = p1b[cN1 + n] - ny, dz = p1b[2 * cN1 + n] - nz;
  float dist = sqrtf(dx * dx + dy * dy + dz * dz);
  // near4 alias: overwrite this row's chunk-0 slot (all reads of it done)
  partA[(0 * cB + b) * cN1 + n] = make_float4(nx, ny, nz, dist);

  double acc1[1];
  acc1[0] = (double)dist;
  reduce_multi(acc1, 1, lds, tid);
  if (tid == 0) dpart[b * cNB2 + bx] = acc1[0];

  // ---------- completion flag (no numeric fan-in through atomics) ----------
  __threadfence();                       // release near4 + dpart
  if (tid == 0) {
    int old = atomicAdd(ctr + b, 1);
    s_last = (old == cNB2 - 1) ? 1 : 0;
  }
  __syncthreads();
  if (!s_last) return;
  __threadfence();                       // acquire other blocks' writes

  // ---------- phase 2: mean (bit-identical serial sum) ----------
  if (tid == 0) {
    double dsum = 0.0;
    for (int i = 0; i < cNB2; ++i) dsum += dpart[b * cNB2 + i];
    s_mean = (float)(dsum * (1.0 / (double)cN1));
  }
  __syncthreads();
  const float meanf = s_mean;

  // ---------- phase 3: 23 moments over all rows, in registers ----------
  double a[23];
  for (int i = 0; i < 23; ++i) a[i] = 0.0;
#pragma unroll 2
  for (int it = 0; it < cNB2; ++it) {
    const int r = it * 256 + tid;
    float4 nn = partA[(0 * cB + b) * cN1 + r];   // near4 alias
    float u = (nn.w - meanf - cEPS) * 1e10f;
    float ind = 1.0f / (1.0f + expf(u));
    double di = (double)ind, di2 = di * di;
    double x1 = (double)p1b[r], y1 = (double)p1b[cN1 + r],
           z1 = (double)p1b[2 * cN1 + r];
    double x2 = (double)nn.x, y2 = (double)nn.y, z2 = (double)nn.z;

    a[0] += di;
    a[1] += di * x1;  a[2] += di * y1;  a[3] += di * z1;
    a[4] += di * x2;  a[5] += di * y2;  a[6] += di * z2;
    a[7] += di2;
    a[8]  += di2 * x1;  a[9]  += di2 * y1;  a[10] += di2 * z1;
    a[11] += di2 * x2;  a[12] += di2 * y2;  a[13] += di2 * z2;
    a[14] += di2 * x1 * x2; a[15] += di2 * x1 * y2; a[16] += di2 * x1 * z2;
    a[17] += di2 * y1 * x2; a[18] += di2 * y1 * y2; a[19] += di2 * y1 * z2;
    a[20] += di2 * z1 * x2; a[21] += di2 * z1 * y2; a[22] += di2 * z1 * z2;
  }
  reduce_multi(a, 23, lds, tid);

  // ---------- phase 4: Kabsch solve (Horn quaternion, Jacobi), lane 0 -----
  if (tid != 0) return;

  double W = a[0];
  double c1[3] = {a[1] / W, a[2] / W, a[3] / W};
  double c2[3] = {a[4] / W, a[5] / W, a[6] / W};
  double H[3][3];
  for (int i = 0; i < 3; ++i)
    for (int j = 0; j < 3; ++j)
      H[i][j] = a[14 + 3 * i + j] - c2[j] * a[8 + i] -
                c1[i] * a[11 + j] + c1[i] * c2[j] * a[7];

  // Horn / Besl-McKay 4x4 quaternion matrix -> Jacobi eigen (6 sweeps)
  double trH = H[0][0] + H[1][1] + H[2][2];
  double Nm[4][4], V[4][4];
  Nm[0][0] = trH;
  Nm[0][1] = Nm[1][0] = H[1][2] - H[2][1];
  Nm[0][2] = Nm[2][0] = H[2][0] - H[0][2];
  Nm[0][3] = Nm[3][0] = H[0][1] - H[1][0];
  Nm[1][1] = 2.0 * H[0][0] - trH;
  Nm[1][2] = Nm[2][1] = H[0][1] + H[1][0];
  Nm[1][3] = Nm[3][1] = H[0][2] + H[2][0];
  Nm[2][2] = 2.0 * H[1][1] - trH;
  Nm[2][3] = Nm[3][2] = H[1][2] + H[2][1];
  Nm[3][3] = 2.0 * H[2][2] - trH;

  for (int i = 0; i < 4; ++i)
    for (int j = 0; j < 4; ++j) V[i][j] = (i == j) ? 1.0 : 0.0;

  for (int sweep = 0; sweep < 6; ++sweep) {
    for (int p = 0; p < 3; ++p) {
      for (int q = p + 1; q < 4; ++q) {
        double apq = Nm[p][q];
        if (fabs(apq) < 1e-300) continue;
        double theta = (Nm[q][q] - Nm[p][p]) / (2.0 * apq);
        double tt = (theta >= 0.0 ? 1.0 : -1.0) /
                    (fabs(theta) + sqrt(theta * theta + 1.0));
        double cc = 1.0 / sqrt(tt * tt + 1.0);
        double ss = tt * cc;
        for (int k = 0; k < 4; ++k) {
          double akp = Nm[k][p], akq = Nm[k][q];
          Nm[k][p] = cc * akp - ss * akq;
          Nm[k][q] = ss * akp + cc * akq;
        }
        for (int k = 0; k < 4; ++k) {
          double apk = Nm[p][k], aqk = Nm[q][k];
          Nm[p][k] = cc * apk - ss * aqk;
          Nm[q][k] = ss * apk + cc * aqk;
        }
        for (int k = 0; k < 4; ++k) {
          double vkp = V[k][p], vkq = V[k][q];
          V[k][p] = cc * vkp - ss * vkq;
          V[k][q] = ss * vkp + cc * vkq;
        }
      }
    }
  }
  int imax = 0;
  for (int i = 1; i < 4; ++i)
    if (Nm[i][i] > Nm[imax][imax]) imax = i;
  double qw = V[0][imax], qx = V[1][imax], qy = V[2][imax], qz = V[3][imax];
  double qn = sqrt(qw * qw + qx * qx + qy * qy + qz * qz);
  qw /= qn; qx /= qn; qy /= qn; qz /= qn;

  double R[3][3];
  R[0][0] = 1.0 - 2.0 * (qy * qy + qz * qz);
  R[0][1] = 2.0 * (qx * qy - qw * qz);
  R[0][2] = 2.0 * (qx * qz + qw * qy);
  R[1][0] = 2.0 * (qx * qy + qw * qz);
  R[1][1] = 1.0 - 2.0 * (qx * qx + qz * qz);
  R[1][2] = 2.0 * (qy * qz - qw * qx);
  R[2][0] = 2.0 * (qx * qz - qw * qy);
  R[2][1] = 2.0 * (qy * qz + qw * qx);
  R[2][2] = 1.0 - 2.0 * (qx * qx + qy * qy);

  // safeguard vs convention flip: objective is tr(R H); transpose if better
  double tr1 = 0.0, tr2 = 0.0;
  for (int i = 0; i < 3; ++i)
    for (int j = 0; j < 3; ++j) {
      tr1 += R[i][j] * H[j][i];
      tr2 += R[j][i] * H[j][i];
    }
  if (tr2 > tr1) {
    for (int i = 0; i < 3; ++i)
      for (int j = i + 1; j < 3; ++j) {
        double tmp = R[i][j]; R[i][j] = R[j][i]; R[j][i] = tmp;
      }
  }

  double tx = c2[0] - (R[0][0] * c1[0] + R[0][1] * c1[1] + R[0][2] * c1[2]);
  double ty = c2[1] - (R[1][0] * c1[0] + R[1][1] * c1[1] + R[1][2] * c1[2]);
  double tz = c2[2] - (R[2][0] * c1[0] + R[2][1] * c1[1] + R[2][2] * c1[2]);

  auto sgn = [](double x) { return x >= 0.0 ? 1.0 : -1.0; };
  double oqw = 0.5 * sqrt(fmax(1.0 + R[0][0] + R[1][1] + R[2][2], 1e-12));
  double oqx = 0.5 * sqrt(fmax(1.0 + R[0][0] - R[1][1] - R[2][2], 1e-12)) *
               sgn(R[2][1] - R[1][2]);
  double oqy = 0.5 * sqrt(fmax(1.0 - R[0][0] + R[1][1] - R[2][2], 1e-12)) *
               sgn(R[0][2] - R[2][0]);
  double oqz = 0.5 * sqrt(fmax(1.0 - R[0][0] - R[1][1] + R[2][2], 1e-12)) *
               sgn(R[1][0] - R[0][1]);

  float* T = out + b * 16;
  T[0]  = (float)R[0][0]; T[1]  = (float)R[0][1]; T[2]  = (float)R[0][2]; T[3]  = (float)tx;
  T[4]  = (float)R[1][0]; T[5]  = (float)R[1][1]; T[6]  = (float)R[1][2]; T[7]  = (float)ty;
  T[8]  = (float)R[2][0]; T[9]  = (float)R[2][1]; T[10] = (float)R[2][2]; T[11] = (float)tz;
  T[12] = 0.f; T[13] = 0.f; T[14] = 0.f; T[15] = 1.f;
  float* Q = out + 128 + b * 4;
  Q[0] = (float)oqw; Q[1] = (float)oqx; Q[2] = (float)oqy; Q[3] = (float)oqz;
  float* Tt = out + 160 + b * 3;
  Tt[0] = (float)tx; Tt[1] = (float)ty; Tt[2] = (float)tz;
}

// ---------------- launch ----------------
extern "C" void kernel_launch(void* const* d_in, const int* in_sizes, int n_in,
                              void* d_out, int out_size, void* d_ws, size_t ws_size,
                              hipStream_t stream) {
  const float* pc1 = (const float*)d_in[0];
  const float* pc2 = (const float*)d_in[1];
  float* out = (float*)d_out;
  char* ws = (char*)d_ws;

  float4* partA = (float4*)ws;
  float*  partM = (float*)(ws + OFF_PARTM);
  double* dpart = (double*)(ws + OFF_DPART);
  int*    ctr   = (int*)(ws + OFF_CTR);

  cpnet_partial<<<dim3(cN1 / 256, cMC, cB), 256, 0, stream>>>(
      pc1, pc2, partA, partM, ctr);
  cpnet_finalize<<<dim3(cNB2, cB), 256, 0, stream>>>(
      pc1, partA, partM, dpart, ctr, out);
}

// Round 2
// 139.171 us; speedup vs baseline: 1.0790x; 1.0790x over previous
//
#include <hip/hip_runtime.h>
#include <math.h>

// CPNet registration: B=8 batches, pc1 (4 x 4096), pc2 (4 x 4096), fp32.
// Outputs: T (8,4,4)=128 | q (8,4)=32 | t (8,3)=24  -> 184 floats concat.
//
// R8: tail reverted to the PROVEN R6 3-kernel chain (K2/K3/K4 verbatim,
// 141.8us total there). K1 rewritten for ILP: each thread owns 4 rows
// (r = k*64+lane), each wave owns 1/4 of the m-chunk. LDS broadcasts and
// (vw+n1k) adds amortize over 4 rows; 4 independent dependency chains
// per lane hide VALU/trans latency. Per-wave sub-softmax partials are
// combined in-block with the same exp2-rescale math K2 uses across
// chunks; partM is bit-identical to R6's, partA differs ~1e-7 relative.

typedef float v2f __attribute__((ext_vector_type(2)));

constexpr int cB  = 8;
constexpr int cN1 = 4096;
constexpr int cN2 = 4096;
constexpr int cMC = 8;               // m-chunks
constexpr int cCHUNK = cN2 / cMC;    // 512
constexpr int cNB2 = cN1 / 256;      // 16 n-blocks for K2/K3
constexpr float cEPS  = 1e-5f;
constexpr float cKK   = 0.34657359027997264f;   // ln2/2 = 1/(FACT*log2(e))
constexpr float cEPSK = cEPS * cKK;             // scaled clamp
constexpr float cUNSC = -1.4426950408889634f;   // -1/ln2 (undo -ln2 packing)

// ---------------- workspace layout (bytes) ----------------
// partA : float4[cMC*cB*cN1] @ 0         (4 MiB; chunk 0 reused as near4)
// partM : float [cMC*cB*cN1] @ 0x400000  (1 MiB)
// dpart : double[cB*16]      @ 0x500000  (1 KiB)
// mpart : double[cB*16*23]   @ 0x500400  (29.4 KiB)
constexpr size_t OFF_PARTM = 0x400000;
constexpr size_t OFF_DPART = 0x500000;
constexpr size_t OFF_MPART = 0x500400;

// ============ K1: 4-rows/thread, wave-split m-range softmax partials =======
__global__ __launch_bounds__(256) void cpnet_partial(
    const float* __restrict__ pc1, const float* __restrict__ pc2,
    float4* __restrict__ partA, float* __restrict__ partM) {
  __shared__ float xs[cCHUNK], ys[cCHUNK], zs[cCHUNK], ws[cCHUNK];
  __shared__ float comb[4][256][5];   // [wave g][row][S,Ax,Ay,Az,M]
  const int tid = threadIdx.x;
  const int lane = tid & 63, g = tid >> 6;
  const int b = blockIdx.z, c = blockIdx.y;
  const int nbase = blockIdx.x * 256;

  // fused pack: (-ln2*x, -ln2*y, -ln2*z, (ln2/2)*|p|^2)
  const float* p2b = pc2 + (size_t)b * 4 * cN2 + c * cCHUNK;
  for (int i = tid; i < cCHUNK; i += 256) {
    float x = p2b[i], y = p2b[cN2 + i], z = p2b[2 * cN2 + i];
    xs[i] = -2.0f * cKK * x;
    ys[i] = -2.0f * cKK * y;
    zs[i] = -2.0f * cKK * z;
    ws[i] = cKK * (x * x + y * y + z * z);
  }
  __syncthreads();

  // 4 rows per thread: r = k*64 + lane (coalesced loads per k)
  const float* p1b = pc1 + (size_t)b * 4 * cN1;
  float x1[4], y1[4], z1[4], n1k[4];
#pragma unroll
  for (int k = 0; k < 4; ++k) {
    int r = nbase + k * 64 + lane;
    x1[k] = p1b[r];
    y1[k] = p1b[cN1 + r];
    z1[k] = p1b[2 * cN1 + r];
    n1k[k] = cKK * (x1[k] * x1[k] + y1[k] * y1[k] + z1[k] * z1[k]);
  }

  // wave g owns m in [g*128, g*128+128)  (64 v2f iterations)
  const v2f* xs2 = (const v2f*)xs + g * 64;
  const v2f* ys2 = (const v2f*)ys + g * 64;
  const v2f* zs2 = (const v2f*)zs + g * 64;
  const v2f* ws2 = (const v2f*)ws + g * 64;

  // pass 1: per-row min dk over this wave's sub-chunk
  v2f dmin2[4];
#pragma unroll
  for (int k = 0; k < 4; ++k) dmin2[k] = (v2f){3.0e38f, 3.0e38f};
#pragma unroll 2
  for (int m = 0; m < 64; ++m) {
    v2f vx = xs2[m], vy = ys2[m], vz = zs2[m], vw = ws2[m];
#pragma unroll
    for (int k = 0; k < 4; ++k) {
      v2f dk = vx * x1[k] + (vy * y1[k] + (vz * z1[k] + (vw + n1k[k])));
      dmin2[k] = __builtin_elementwise_min(dmin2[k], dk);
    }
  }
  float M[4];
#pragma unroll
  for (int k = 0; k < 4; ++k)
    M[k] = __builtin_amdgcn_rcpf(fmaxf(fminf(dmin2[k].x, dmin2[k].y), cEPSK));

  // pass 2: exp-sum + weighted accumulators relative to per-sub-chunk M
  v2f S2[4], Ax2[4], Ay2[4], Az2[4];
#pragma unroll
  for (int k = 0; k < 4; ++k) {
    S2[k] = (v2f){0.f, 0.f}; Ax2[k] = (v2f){0.f, 0.f};
    Ay2[k] = (v2f){0.f, 0.f}; Az2[k] = (v2f){0.f, 0.f};
  }
  const v2f EPS2 = {cEPSK, cEPSK};
#pragma unroll 2
  for (int m = 0; m < 64; ++m) {
    v2f vx = xs2[m], vy = ys2[m], vz = zs2[m], vw = ws2[m];
#pragma unroll
    for (int k = 0; k < 4; ++k) {
      v2f dk = vx * x1[k] + (vy * y1[k] + (vz * z1[k] + (vw + n1k[k])));
      dk = __builtin_elementwise_max(dk, EPS2);
      v2f s2v;
      s2v.x = __builtin_amdgcn_rcpf(dk.x);
      s2v.y = __builtin_amdgcn_rcpf(dk.y);
      v2f e;
      e.x = __builtin_amdgcn_exp2f(s2v.x - M[k]);
      e.y = __builtin_amdgcn_exp2f(s2v.y - M[k]);
      S2[k] += e;
      Ax2[k] += e * vx;
      Ay2[k] += e * vy;
      Az2[k] += e * vz;
    }
  }

  // stash per-(wave, row) partials
#pragma unroll
  for (int k = 0; k < 4; ++k) {
    int r = k * 64 + lane;
    comb[g][r][0] = S2[k].x + S2[k].y;
    comb[g][r][1] = Ax2[k].x + Ax2[k].y;
    comb[g][r][2] = Ay2[k].x + Ay2[k].y;
    comb[g][r][3] = Az2[k].x + Az2[k].y;
    comb[g][r][4] = M[k];
  }
  __syncthreads();

  // per-row combine over the 4 waves (same rescale math as K2 cross-chunk)
  float m0 = comb[0][tid][4], m1 = comb[1][tid][4],
        m2 = comb[2][tid][4], m3 = comb[3][tid][4];
  float mrow = fmaxf(fmaxf(m0, m1), fmaxf(m2, m3));
  float S = 0.f, Ax = 0.f, Ay = 0.f, Az = 0.f;
#pragma unroll
  for (int gg = 0; gg < 4; ++gg) {
    float w = exp2f(comb[gg][tid][4] - mrow);
    S  += comb[gg][tid][0] * w;
    Ax += comb[gg][tid][1] * w;
    Ay += comb[gg][tid][2] * w;
    Az += comb[gg][tid][3] * w;
  }
  const int idx = (c * cB + b) * cN1 + nbase + tid;
  partA[idx] = make_float4(Ax, Ay, Az, S);
  partM[idx] = mrow;
}

// ---------------- batched block reduce (256 thr, 4 waves, doubles) ---------
__device__ __forceinline__ void reduce_multi(double* v, int nv, double* lds,
                                             int tid) {
  const int lane = tid & 63, w = tid >> 6;
  for (int i = 0; i < nv; ++i) {
    double x = v[i];
    for (int s = 32; s > 0; s >>= 1) x += __shfl_xor(x, s, 64);
    if (lane == 0) lds[i * 4 + w] = x;
  }
  __syncthreads();
  if (tid < nv)
    lds[tid * 4] = lds[tid * 4] + lds[tid * 4 + 1] + lds[tid * 4 + 2] +
                   lds[tid * 4 + 3];
  __syncthreads();
  for (int i = 0; i < nv; ++i) v[i] = lds[i * 4];
  __syncthreads();
}

// ============ K2: combine chunks -> near4 (aliased) + per-block dist sum ===
__global__ __launch_bounds__(256) void cpnet_combine(
    const float* __restrict__ pc1, float4* partA,
    const float* __restrict__ partM, double* __restrict__ dpart) {
  __shared__ double lds[32 * 4];
  const int tid = threadIdx.x;
  const int bx = blockIdx.x, b = blockIdx.y;
  const int n = bx * 256 + tid;

  float Ms[cMC];
  float g = -3.0e38f;
#pragma unroll
  for (int c = 0; c < cMC; ++c) {
    Ms[c] = partM[(c * cB + b) * cN1 + n];
    g = fmaxf(g, Ms[c]);
  }
  float S = 0.f, nx = 0.f, ny = 0.f, nz = 0.f;
#pragma unroll
  for (int c = 0; c < cMC; ++c) {
    float w = exp2f(Ms[c] - g);
    float4 a = partA[(c * cB + b) * cN1 + n];
    S += a.w * w; nx += a.x * w; ny += a.y * w; nz += a.z * w;
  }
  float inv = cUNSC / S;         // undo -ln2 packing + softmax normalize
  nx *= inv; ny *= inv; nz *= inv;
  const float* p1b = pc1 + (size_t)b * 4 * cN1;
  float dx = p1b[n] - nx, dy = p1b[cN1 + n] - ny, dz = p1b[2 * cN1 + n] - nz;
  float dist = sqrtf(dx * dx + dy * dy + dz * dz);
  // near4 alias: overwrite this row's chunk-0 slot (all reads of it done)
  partA[(0 * cB + b) * cN1 + n] = make_float4(nx, ny, nz, dist);

  double acc[1];
  acc[0] = (double)dist;
  reduce_multi(acc, 1, lds, tid);
  if (tid == 0) dpart[b * cNB2 + bx] = acc[0];
}

// ============ K3: inlier mask + 23 moments, per-block partials =============
__global__ __launch_bounds__(256) void cpnet_moments(
    const float* __restrict__ pc1, const float4* __restrict__ partA,
    const double* __restrict__ dpart, double* __restrict__ mpart) {
  __shared__ double lds[32 * 4];
  const int tid = threadIdx.x;
  const int bx = blockIdx.x, b = blockIdx.y;
  const int n = bx * 256 + tid;

  // deterministic mean: same serial sum in every block
  double dsum = 0.0;
  for (int i = 0; i < cNB2; ++i) dsum += dpart[b * cNB2 + i];
  const float meanf = (float)(dsum * (1.0 / (double)cN1));

  float4 nn = partA[(0 * cB + b) * cN1 + n];   // near4 alias
  float u = (nn.w - meanf - cEPS) * 1e10f;
  float ind = 1.0f / (1.0f + expf(u));
  const float* p1b = pc1 + (size_t)b * 4 * cN1;
  double di = (double)ind, di2 = di * di;
  double x1 = (double)p1b[n], y1 = (double)p1b[cN1 + n],
         z1 = (double)p1b[2 * cN1 + n];
  double x2 = (double)nn.x, y2 = (double)nn.y, z2 = (double)nn.z;

  double a[23];
  a[0] = di;
  a[1] = di * x1;  a[2] = di * y1;  a[3] = di * z1;
  a[4] = di * x2;  a[5] = di * y2;  a[6] = di * z2;
  a[7] = di2;
  a[8]  = di2 * x1;  a[9]  = di2 * y1;  a[10] = di2 * z1;
  a[11] = di2 * x2;  a[12] = di2 * y2;  a[13] = di2 * z2;
  a[14] = di2 * x1 * x2; a[15] = di2 * x1 * y2; a[16] = di2 * x1 * z2;
  a[17] = di2 * y1 * x2; a[18] = di2 * y1 * y2; a[19] = di2 * y1 * z2;
  a[20] = di2 * z1 * x2; a[21] = di2 * z1 * y2; a[22] = di2 * z1 * z2;

  reduce_multi(a, 23, lds, tid);
  if (tid == 0) {
    double* mb = mpart + (size_t)(b * cNB2 + bx) * 23;
    for (int i = 0; i < 23; ++i) mb[i] = a[i];
  }
}

// ============ K4: per-batch Kabsch solve (Horn quaternion, Jacobi) =========
__global__ __launch_bounds__(64) void cpnet_solve(
    const double* __restrict__ mpart, float* __restrict__ out) {
  const int b = blockIdx.x;
  if (threadIdx.x != 0) return;

  double acc[23];
  for (int i = 0; i < 23; ++i) acc[i] = 0.0;
  for (int k = 0; k < cNB2; ++k) {
    const double* mb = mpart + (size_t)(b * cNB2 + k) * 23;
    for (int i = 0; i < 23; ++i) acc[i] += mb[i];
  }

  double W = acc[0];
  double c1[3] = {acc[1] / W, acc[2] / W, acc[3] / W};
  double c2[3] = {acc[4] / W, acc[5] / W, acc[6] / W};
  double H[3][3];
  for (int i = 0; i < 3; ++i)
    for (int j = 0; j < 3; ++j)
      H[i][j] = acc[14 + 3 * i + j] - c2[j] * acc[8 + i] -
                c1[i] * acc[11 + j] + c1[i] * c2[j] * acc[7];

  // Horn / Besl-McKay 4x4 quaternion matrix -> Jacobi eigen (6 sweeps)
  double trH = H[0][0] + H[1][1] + H[2][2];
  double Nm[4][4], V[4][4];
  Nm[0][0] = trH;
  Nm[0][1] = Nm[1][0] = H[1][2] - H[2][1];
  Nm[0][2] = Nm[2][0] = H[2][0] - H[0][2];
  Nm[0][3] = Nm[3][0] = H[0][1] - H[1][0];
  Nm[1][1] = 2.0 * H[0][0] - trH;
  Nm[1][2] = Nm[2][1] = H[0][1] + H[1][0];
  Nm[1][3] = Nm[3][1] = H[0][2] + H[2][0];
  Nm[2][2] = 2.0 * H[1][1] - trH;
  Nm[2][3] = Nm[3][2] = H[1][2] + H[2][1];
  Nm[3][3] = 2.0 * H[2][2] - trH;

  for (int i = 0; i < 4; ++i)
    for (int j = 0; j < 4; ++j) V[i][j] = (i == j) ? 1.0 : 0.0;

  for (int sweep = 0; sweep < 6; ++sweep) {
    for (int p = 0; p < 3; ++p) {
      for (int q = p + 1; q < 4; ++q) {
        double apq = Nm[p][q];
        if (fabs(apq) < 1e-300) continue;
        double theta = (Nm[q][q] - Nm[p][p]) / (2.0 * apq);
        double tt = (theta >= 0.0 ? 1.0 : -1.0) /
                    (fabs(theta) + sqrt(theta * theta + 1.0));
        double cc = 1.0 / sqrt(tt * tt + 1.0);
        double ss = tt * cc;
        for (int k = 0; k < 4; ++k) {
          double akp = Nm[k][p], akq = Nm[k][q];
          Nm[k][p] = cc * akp - ss * akq;
          Nm[k][q] = ss * akp + cc * akq;
        }
        for (int k = 0; k < 4; ++k) {
          double apk = Nm[p][k], aqk = Nm[q][k];
          Nm[p][k] = cc * apk - ss * aqk;
          Nm[q][k] = ss * apk + cc * aqk;
        }
        for (int k = 0; k < 4; ++k) {
          double vkp = V[k][p], vkq = V[k][q];
          V[k][p] = cc * vkp - ss * vkq;
          V[k][q] = ss * vkp + cc * vkq;
        }
      }
    }
  }
  int imax = 0;
  for (int i = 1; i < 4; ++i)
    if (Nm[i][i] > Nm[imax][imax]) imax = i;
  double qw = V[0][imax], qx = V[1][imax], qy = V[2][imax], qz = V[3][imax];
  double qn = sqrt(qw * qw + qx * qx + qy * qy + qz * qz);
  qw /= qn; qx /= qn; qy /= qn; qz /= qn;

  double R[3][3];
  R[0][0] = 1.0 - 2.0 * (qy * qy + qz * qz);
  R[0][1] = 2.0 * (qx * qy - qw * qz);
  R[0][2] = 2.0 * (qx * qz + qw * qy);
  R[1][0] = 2.0 * (qx * qy + qw * qz);
  R[1][1] = 1.0 - 2.0 * (qx * qx + qz * qz);
  R[1][2] = 2.0 * (qy * qz - qw * qx);
  R[2][0] = 2.0 * (qx * qz - qw * qy);
  R[2][1] = 2.0 * (qy * qz + qw * qx);
  R[2][2] = 1.0 - 2.0 * (qx * qx + qy * qy);

  // safeguard vs convention flip: objective is tr(R H); transpose if better
  double tr1 = 0.0, tr2 = 0.0;
  for (int i = 0; i < 3; ++i)
    for (int j = 0; j < 3; ++j) {
      tr1 += R[i][j] * H[j][i];
      tr2 += R[j][i] * H[j][i];
    }
  if (tr2 > tr1) {
    for (int i = 0; i < 3; ++i)
      for (int j = i + 1; j < 3; ++j) {
        double tmp = R[i][j]; R[i][j] = R[j][i]; R[j][i] = tmp;
      }
  }

  double tx = c2[0] - (R[0][0] * c1[0] + R[0][1] * c1[1] + R[0][2] * c1[2]);
  double ty = c2[1] - (R[1][0] * c1[0] + R[1][1] * c1[1] + R[1][2] * c1[2]);
  double tz = c2[2] - (R[2][0] * c1[0] + R[2][1] * c1[1] + R[2][2] * c1[2]);

  auto sgn = [](double x) { return x >= 0.0 ? 1.0 : -1.0; };
  double oqw = 0.5 * sqrt(fmax(1.0 + R[0][0] + R[1][1] + R[2][2], 1e-12));
  double oqx = 0.5 * sqrt(fmax(1.0 + R[0][0] - R[1][1] - R[2][2], 1e-12)) *
               sgn(R[2][1] - R[1][2]);
  double oqy = 0.5 * sqrt(fmax(1.0 - R[0][0] + R[1][1] - R[2][2], 1e-12)) *
               sgn(R[0][2] - R[2][0]);
  double oqz = 0.5 * sqrt(fmax(1.0 - R[0][0] - R[1][1] + R[2][2], 1e-12)) *
               sgn(R[1][0] - R[0][1]);

  float* T = out + b * 16;
  T[0]  = (float)R[0][0]; T[1]  = (float)R[0][1]; T[2]  = (float)R[0][2]; T[3]  = (float)tx;
  T[4]  = (float)R[1][0]; T[5]  = (float)R[1][1]; T[6]  = (float)R[1][2]; T[7]  = (float)ty;
  T[8]  = (float)R[2][0]; T[9]  = (float)R[2][1]; T[10] = (float)R[2][2]; T[11] = (float)tz;
  T[12] = 0.f; T[13] = 0.f; T[14] = 0.f; T[15] = 1.f;
  float* Q = out + 128 + b * 4;
  Q[0] = (float)oqw; Q[1] = (float)oqx; Q[2] = (float)oqy; Q[3] = (float)oqz;
  float* Tt = out + 160 + b * 3;
  Tt[0] = (float)tx; Tt[1] = (float)ty; Tt[2] = (float)tz;
}

// ---------------- launch ----------------
extern "C" void kernel_launch(void* const* d_in, const int* in_sizes, int n_in,
                              void* d_out, int out_size, void* d_ws, size_t ws_size,
                              hipStream_t stream) {
  const float* pc1 = (const float*)d_in[0];
  const float* pc2 = (const float*)d_in[1];
  float* out = (float*)d_out;
  char* ws = (char*)d_ws;

  float4* partA = (float4*)ws;
  float*  partM = (float*)(ws + OFF_PARTM);
  double* dpart = (double*)(ws + OFF_DPART);
  double* mpart = (double*)(ws + OFF_MPART);

  cpnet_partial<<<dim3(cN1 / 256, cMC, cB), 256, 0, stream>>>(pc1, pc2,
                                                              partA, partM);
  cpnet_combine<<<dim3(cNB2, cB), 256, 0, stream>>>(pc1, partA, partM, dpart);
  cpnet_moments<<<dim3(cNB2, cB), 256, 0, stream>>>(pc1, partA, dpart, mpart);
  cpnet_solve<<<cB, 64, 0, stream>>>(mpart, out);
}